// Round 6
// baseline (1186.963 us; speedup 1.0000x reference)
//
#include <hip/hip_runtime.h>
#include <math.h>

typedef unsigned short u16;
typedef short short8 __attribute__((ext_vector_type(8)));
typedef float f32x4 __attribute__((ext_vector_type(4)));
typedef unsigned short us4 __attribute__((ext_vector_type(4)));

#define NTOK 8192
#define NEXP 8

__device__ __forceinline__ u16 f2bf(float f) {
  union { float f; unsigned u; } v; v.f = f;
  unsigned r = v.u + 0x7FFFu + ((v.u >> 16) & 1u);
  return (u16)(r >> 16);
}
__device__ __forceinline__ float bf2f(u16 u) {
  union { unsigned u; float f; } v; v.u = ((unsigned)u) << 16; return v.f;
}
__device__ __forceinline__ void gload16(const u16* src, u16* ldsDst) {
  __builtin_amdgcn_global_load_lds(
    (const __attribute__((address_space(1))) unsigned int*)(const void*)src,
    (__attribute__((address_space(3))) unsigned int*)(void*)ldsDst, 16, 0, 0);
}
// fast gelu: A&S 7.1.26 erf (|err|<=1.5e-7)
__device__ __forceinline__ float gelu_f(float v) {
  float ax = fabsf(v) * 0.70710678f;
  float t = __builtin_amdgcn_rcpf(1.0f + 0.3275911f * ax);
  float p = t * (0.254829592f + t * (-0.284496736f + t * (1.421413741f +
            t * (-1.453152027f + t * 1.061405429f))));
  float er = 1.0f - p * __expf(-ax * ax);
  er = copysignf(er, v);
  return 0.5f * v * (1.0f + er);
}

// ---------------- elementwise fp32 -> bf16 cast ----------------
__global__ void cast_kernel(const float* __restrict__ in, u16* __restrict__ out, int n4) {
  int i = blockIdx.x * blockDim.x + threadIdx.x;
  if (i < n4) {
    float4 v = ((const float4*)in)[i];
    us4 o;
    o[0] = f2bf(v.x); o[1] = f2bf(v.y); o[2] = f2bf(v.z); o[3] = f2bf(v.w);
    ((us4*)out)[i] = o;
  }
}

// ------- 64x64 tiled transpose+cast: fp32 in[R][C] -> bf16 out[C][R], blockIdx.z = expert -------
__global__ void transpose_cast(const float* __restrict__ in, u16* __restrict__ out, int R, int C) {
  __shared__ float tile[64][65];
  const size_t eoff = (size_t)blockIdx.z * (size_t)R * (size_t)C;
  in += eoff; out += eoff;
  const int rb = blockIdx.y * 64, cb = blockIdx.x * 64;
  const int tid = threadIdx.x;
  const int lr4 = tid >> 4;
  const int lc4 = (tid & 15) * 4;
#pragma unroll
  for (int p = 0; p < 4; ++p) {
    float4 v = *(const float4*)&in[(size_t)(rb + p * 16 + lr4) * C + cb + lc4];
    tile[p * 16 + lr4][lc4 + 0] = v.x;
    tile[p * 16 + lr4][lc4 + 1] = v.y;
    tile[p * 16 + lr4][lc4 + 2] = v.z;
    tile[p * 16 + lr4][lc4 + 3] = v.w;
  }
  __syncthreads();
  const int oc = tid >> 3;
  const int orr = (tid & 7) * 8;
#pragma unroll
  for (int p = 0; p < 2; ++p) {
    int c = p * 32 + oc;
    short8 o;
#pragma unroll
    for (int j = 0; j < 8; ++j) o[j] = (short)f2bf(tile[orr + j][c]);
    *(short8*)&out[(size_t)(cb + c) * R + rb + orr] = o;
  }
}

// ---------------- LayerNorm1: fp32 row -> bf16 row ----------------
__global__ void ln1_kernel(const float* __restrict__ x, const float* __restrict__ w,
                           const float* __restrict__ b, u16* __restrict__ xn) {
  const int t = blockIdx.x, tid = threadIdx.x;
  __shared__ float red[8];
  float4 v = ((const float4*)(x + (size_t)t * 1024))[tid];
  float s  = v.x + v.y + v.z + v.w;
  float sq = v.x*v.x + v.y*v.y + v.z*v.z + v.w*v.w;
#pragma unroll
  for (int m = 1; m < 64; m <<= 1) { s += __shfl_xor(s, m, 64); sq += __shfl_xor(sq, m, 64); }
  if ((tid & 63) == 0) { red[tid >> 6] = s; red[4 + (tid >> 6)] = sq; }
  __syncthreads();
  float S = red[0] + red[1] + red[2] + red[3];
  float Q = red[4] + red[5] + red[6] + red[7];
  float mu  = S * (1.0f / 1024.0f);
  float var = Q * (1.0f / 1024.0f) - mu * mu;
  float inv = rsqrtf(var + 1e-5f);
  float4 wv = ((const float4*)w)[tid];
  float4 bv = ((const float4*)b)[tid];
  us4 o;
  o[0] = f2bf((v.x - mu) * inv * wv.x + bv.x);
  o[1] = f2bf((v.y - mu) * inv * wv.y + bv.y);
  o[2] = f2bf((v.z - mu) * inv * wv.z + bv.z);
  o[3] = f2bf((v.w - mu) * inv * wv.w + bv.w);
  ((us4*)(xn + (size_t)t * 1024))[tid] = o;
}

// -------- LayerNorm2 + gate + top-2 routing (fp32 gate for routing fidelity) --------
__global__ void ln2_gate_kernel(const float* __restrict__ x2, const float* __restrict__ w,
                                const float* __restrict__ b, const float* __restrict__ gw,
                                const float* __restrict__ gb, u16* __restrict__ xn2,
                                int* __restrict__ cnt, int* __restrict__ list_tok,
                                float* __restrict__ list_prob, int* __restrict__ tok2slot) {
  const int t = blockIdx.x, tid = threadIdx.x;
  __shared__ float red[8];
  __shared__ float logits[NEXP];
  __shared__ float xrow[1024];
  float4 v = ((const float4*)(x2 + (size_t)t * 1024))[tid];
  float s  = v.x + v.y + v.z + v.w;
  float sq = v.x*v.x + v.y*v.y + v.z*v.z + v.w*v.w;
#pragma unroll
  for (int m = 1; m < 64; m <<= 1) { s += __shfl_xor(s, m, 64); sq += __shfl_xor(sq, m, 64); }
  if ((tid & 63) == 0) { red[tid >> 6] = s; red[4 + (tid >> 6)] = sq; }
  __syncthreads();
  float S = red[0] + red[1] + red[2] + red[3];
  float Q = red[4] + red[5] + red[6] + red[7];
  float mu  = S * (1.0f / 1024.0f);
  float var = Q * (1.0f / 1024.0f) - mu * mu;
  float inv = rsqrtf(var + 1e-5f);
  float4 wv = ((const float4*)w)[tid];
  float4 bv = ((const float4*)b)[tid];
  float n0 = (v.x - mu) * inv * wv.x + bv.x;
  float n1 = (v.y - mu) * inv * wv.y + bv.y;
  float n2 = (v.z - mu) * inv * wv.z + bv.z;
  float n3 = (v.w - mu) * inv * wv.w + bv.w;
  xrow[tid*4+0] = n0; xrow[tid*4+1] = n1; xrow[tid*4+2] = n2; xrow[tid*4+3] = n3;
  us4 o; o[0] = f2bf(n0); o[1] = f2bf(n1); o[2] = f2bf(n2); o[3] = f2bf(n3);
  ((us4*)(xn2 + (size_t)t * 1024))[tid] = o;
  __syncthreads();
  int e = tid >> 5, l32 = tid & 31;
  const float* gwe = gw + e * 1024;
  float part = 0.0f;
  for (int i = l32; i < 1024; i += 32) part += xrow[i] * gwe[i];
#pragma unroll
  for (int m = 1; m < 32; m <<= 1) part += __shfl_xor(part, m, 64);
  if (l32 == 0) logits[e] = part + gb[e];
  __syncthreads();
  if (tid == 0) {
    float v0 = -1e30f; int e0 = 0;
#pragma unroll
    for (int i = 0; i < NEXP; ++i) { float L = logits[i]; if (L > v0) { v0 = L; e0 = i; } }
    float v1 = -1e30f; int e1 = 0;
#pragma unroll
    for (int i = 0; i < NEXP; ++i) { if (i == e0) continue; float L = logits[i]; if (L > v1) { v1 = L; e1 = i; } }
    float texp = expf(v1 - v0);
    float p0 = 1.0f / (1.0f + texp);
    float p1 = texp / (1.0f + texp);
    int s0 = atomicAdd(&cnt[e0], 1);
    list_tok[e0 * NTOK + s0] = t; list_prob[e0 * NTOK + s0] = p0;
    int s1 = atomicAdd(&cnt[e1], 1);
    list_tok[e1 * NTOK + s1] = t; list_prob[e1 * NTOK + s1] = p1;
    if (tok2slot) {
      tok2slot[2 * t]     = e0 * NTOK + s0;
      tok2slot[2 * t + 1] = e1 * NTOK + s1;
    }
  }
}

// ----- plan kernel: meta[0..7]=slotBase, meta[8]=planCount, meta[16+2i]=e, meta[17+2i]=m0 -----
__global__ void plan_kernel(const int* __restrict__ cnt, int* __restrict__ meta) {
  if (threadIdx.x == 0) {
    int base = 0, p = 0;
    for (int e = 0; e < NEXP; ++e) {
      meta[e] = base;
      int c = cnt[e];
      base += c;
      int nm = (c + 127) >> 7;
      for (int i = 0; i < nm; ++i) { meta[16 + 2 * p] = e; meta[17 + 2 * p] = i << 7; ++p; }
    }
    meta[8] = p;
  }
}

// ---------------- flash attention: one (b,h), 64 q-rows per block ----------------
__launch_bounds__(256)
__global__ void attn_kernel(const u16* __restrict__ qkv, u16* __restrict__ ctx) {
  const int bh = blockIdx.y;
  const int b = bh >> 4, h = bh & 15;
  const int q0 = blockIdx.x * 64;
  const int tokBase = b * 1024;
  __shared__ __align__(16) u16 Qs[64 * 72];
  __shared__ __align__(16) u16 Ks[64 * 72];
  __shared__ __align__(16) u16 Vts[64 * 72];
  __shared__ __align__(16) u16 Ps[64 * 72];
  const int tid = threadIdx.x;
  const int wave = tid >> 6, lane = tid & 63, g = lane >> 4, lr = lane & 15;

  {
    int r = tid >> 2, d0 = (tid & 3) * 16;
    const u16* src = qkv + (size_t)(tokBase + q0 + r) * 3072 + h * 64 + d0;
    *(short8*)&Qs[r * 72 + d0]     = *(const short8*)src;
    *(short8*)&Qs[r * 72 + d0 + 8] = *(const short8*)(src + 8);
  }
  __syncthreads();
  short8 aq0 = *(const short8*)&Qs[(wave * 16 + lr) * 72 + g * 8];
  short8 aq1 = *(const short8*)&Qs[(wave * 16 + lr) * 72 + 32 + g * 8];

  const f32x4 zf = {0.f, 0.f, 0.f, 0.f};
  f32x4 Ofr[4] = {zf, zf, zf, zf};
  float m_run[4], l_run[4];
#pragma unroll
  for (int r = 0; r < 4; ++r) { m_run[r] = -1e30f; l_run[r] = 0.f; }

  for (int kt = 0; kt < 1024; kt += 64) {
    __syncthreads();
    {
      int r = tid >> 2, d0 = (tid & 3) * 16;
      const u16* ksrc = qkv + (size_t)(tokBase + kt + r) * 3072 + 1024 + h * 64 + d0;
      *(short8*)&Ks[r * 72 + d0]     = *(const short8*)ksrc;
      *(short8*)&Ks[r * 72 + d0 + 8] = *(const short8*)(ksrc + 8);
      const u16* vsrc = qkv + (size_t)(tokBase + kt + r) * 3072 + 2048 + h * 64 + d0;
      short8 v0 = *(const short8*)vsrc, v1 = *(const short8*)(vsrc + 8);
#pragma unroll
      for (int j = 0; j < 8; ++j) Vts[(d0 + j) * 72 + r] = (u16)v0[j];
#pragma unroll
      for (int j = 0; j < 8; ++j) Vts[(d0 + 8 + j) * 72 + r] = (u16)v1[j];
    }
    __syncthreads();
    f32x4 sf[4];
#pragma unroll
    for (int n = 0; n < 4; ++n) sf[n] = zf;
#pragma unroll
    for (int n = 0; n < 4; ++n) {
      short8 bk0 = *(const short8*)&Ks[(n * 16 + lr) * 72 + g * 8];
      short8 bk1 = *(const short8*)&Ks[(n * 16 + lr) * 72 + 32 + g * 8];
      sf[n] = __builtin_amdgcn_mfma_f32_16x16x32_bf16(aq0, bk0, sf[n], 0, 0, 0);
      sf[n] = __builtin_amdgcn_mfma_f32_16x16x32_bf16(aq1, bk1, sf[n], 0, 0, 0);
    }
#pragma unroll
    for (int n = 0; n < 4; ++n)
#pragma unroll
      for (int r = 0; r < 4; ++r) sf[n][r] *= 0.125f;
    float mnew[4], sc[4];
#pragma unroll
    for (int r = 0; r < 4; ++r) {
      float t0 = fmaxf(fmaxf(sf[0][r], sf[1][r]), fmaxf(sf[2][r], sf[3][r]));
#pragma unroll
      for (int msk = 1; msk < 16; msk <<= 1) t0 = fmaxf(t0, __shfl_xor(t0, msk, 64));
      mnew[r] = fmaxf(m_run[r], t0);
      sc[r] = __expf(m_run[r] - mnew[r]);
      m_run[r] = mnew[r];
    }
#pragma unroll
    for (int n = 0; n < 4; ++n)
#pragma unroll
      for (int r = 0; r < 4; ++r) sf[n][r] = __expf(sf[n][r] - mnew[r]);
#pragma unroll
    for (int r = 0; r < 4; ++r) {
      float s0 = sf[0][r] + sf[1][r] + sf[2][r] + sf[3][r];
#pragma unroll
      for (int msk = 1; msk < 16; msk <<= 1) s0 += __shfl_xor(s0, msk, 64);
      l_run[r] = l_run[r] * sc[r] + s0;
    }
#pragma unroll
    for (int nd = 0; nd < 4; ++nd)
#pragma unroll
      for (int r = 0; r < 4; ++r) Ofr[nd][r] *= sc[r];
#pragma unroll
    for (int n = 0; n < 4; ++n)
#pragma unroll
      for (int r = 0; r < 4; ++r)
        Ps[(wave * 16 + g * 4 + r) * 72 + n * 16 + lr] = f2bf(sf[n][r]);
    __syncthreads();
    short8 ap0 = *(const short8*)&Ps[(wave * 16 + lr) * 72 + g * 8];
    short8 ap1 = *(const short8*)&Ps[(wave * 16 + lr) * 72 + 32 + g * 8];
#pragma unroll
    for (int nd = 0; nd < 4; ++nd) {
      short8 bv0 = *(const short8*)&Vts[(nd * 16 + lr) * 72 + g * 8];
      short8 bv1 = *(const short8*)&Vts[(nd * 16 + lr) * 72 + 32 + g * 8];
      Ofr[nd] = __builtin_amdgcn_mfma_f32_16x16x32_bf16(ap0, bv0, Ofr[nd], 0, 0, 0);
      Ofr[nd] = __builtin_amdgcn_mfma_f32_16x16x32_bf16(ap1, bv1, Ofr[nd], 0, 0, 0);
    }
  }
#pragma unroll
  for (int nd = 0; nd < 4; ++nd)
#pragma unroll
    for (int r = 0; r < 4; ++r) {
      int tok = tokBase + q0 + wave * 16 + g * 4 + r;
      int col = h * 64 + nd * 16 + lr;
      ctx[(size_t)tok * 1024 + col] = f2bf(Ofr[nd][r] / l_run[r]);
    }
}

// ======= 128x256xBK64 bf16 GEMM, C = A @ B^T, 8 waves (2m x 4n), m201-style 8-phase =======
// Per K-tile: 4 phases {ds_read quadrant; [stage]; barrier; lgkmcnt(0); setprio(1); 8 MFMA; setprio(0); barrier}
//   P1: read A m01 + B n01   P2: read B n23 (stage none)
//   P3: read A m23, stage B(t+2) [B(t) LDS dead after P2]
//   P4: stage A(t+2) [A(t) dead after P3], vmcnt(6)=one K-tile outstanding (tail: 0)
// MMAJOR: consecutive remapped wg share the B panel (L2-resident); else share A panel.
// EPI 0: qkv (bias, bf16)  1: outproj (bias+resid, fp32)  2: moe1 (gather, gelu)
// EPI 3: moe2 -> part bf16   4: moe2 atomic fallback
template<int EPI, bool MMAJOR>
__launch_bounds__(512, 1)
__global__ void gemmT(const u16* __restrict__ Abase, const u16* __restrict__ Bbase,
                      int K, int lda, int N, int ldc,
                      const float* __restrict__ bias,
                      const float* __restrict__ resid,
                      float* __restrict__ outF,
                      u16* __restrict__ outB,
                      const int* __restrict__ cnt,
                      const int* __restrict__ meta,
                      const int* __restrict__ list_tok,
                      const float* __restrict__ list_prob) {
  // bijective XCD-aware remap, then panel-major decode
  const int gx = gridDim.x, gy = gridDim.y;
  int nwg = gx * gy;
  int orig = blockIdx.x + blockIdx.y * gx;
  int q8 = nwg >> 3, r8 = nwg & 7, xcd = orig & 7, lid = orig >> 3;
  int wg = (xcd < r8 ? xcd * (q8 + 1) : r8 * (q8 + 1) + (xcd - r8) * q8) + lid;
  int bx, by;
  if (MMAJOR) { by = wg % gy; bx = wg / gy; } else { bx = wg % gx; by = wg / gx; }
  const int n0 = bx * 256;

  int m0, e = 0, M = NTOK, slotBase = 0;
  const u16* Bw = Bbase;
  const float* biasp = bias;
  if constexpr (EPI >= 2) {
    if (by >= meta[8]) return;
    e = meta[16 + 2 * by];
    m0 = meta[17 + 2 * by];
    M = cnt[e];
    slotBase = meta[e];
    Bw += (size_t)e * (size_t)N * (size_t)K;
    biasp = bias + (size_t)e * N;
  } else {
    m0 = by * 128;
  }

  __shared__ __align__(16) u16 As[2][8192];    // 2 x 128x64
  __shared__ __align__(16) u16 Bs[2][16384];   // 2 x 256x64

  const int tid = threadIdx.x;
  const int wave = tid >> 6, lane = tid & 63, g = lane >> 4, lr = lane & 15;
  const int wm = wave >> 2, wn = wave & 3;

  // staging offsets. LDS[row][c] = global[row][c ^ (row&7)], chunks of 8 elems (16B)
  unsigned aoff[2], boff[4];
#pragma unroll
  for (int i = 0; i < 2; ++i) {
    int ci = i * 512 + tid;
    int row = ci >> 3, c = ci & 7;
    int lc = c ^ (row & 7);
    int arow;
    if constexpr (EPI == 2) {
      int ridx = m0 + row; if (ridx > M - 1) ridx = M - 1;
      arow = list_tok[e * NTOK + ridx];
    } else if constexpr (EPI >= 3) {
      int ridx = m0 + row; if (ridx > M - 1) ridx = M - 1;
      arow = slotBase + ridx;
    } else {
      arow = m0 + row;
    }
    aoff[i] = (unsigned)arow * (unsigned)lda + (unsigned)(lc << 3);
  }
#pragma unroll
  for (int i = 0; i < 4; ++i) {
    int ci = i * 512 + tid;
    int row = ci >> 3, c = ci & 7;
    int lc = c ^ (row & 7);
    boff[i] = (unsigned)(n0 + row) * (unsigned)K + (unsigned)(lc << 3);
  }

  const int NT = K >> 6;

#define S_A(T) do { int _t = (T); if (_t < NT) { int _b = _t & 1; int _kt = _t << 6; \
    gload16(Abase + aoff[0] + _kt, &As[_b][(0 * 512 + wave * 64) << 3]); \
    gload16(Abase + aoff[1] + _kt, &As[_b][(1 * 512 + wave * 64) << 3]); } } while (0)
#define S_B(T) do { int _t = (T); if (_t < NT) { int _b = _t & 1; int _kt = _t << 6; \
    _Pragma("unroll") for (int i = 0; i < 4; ++i) \
      gload16(Bw + boff[i] + _kt, &Bs[_b][(i * 512 + wave * 64) << 3]); } } while (0)

  const int sw = lr & 7;
  const int arb = (wm * 64 + lr) * 64;
  const int brb = (wn * 64 + lr) * 64;
  const int sk0 = (g ^ sw) * 8;
  const int sk1 = ((4 + g) ^ sw) * 8;

  const f32x4 zf = {0.f, 0.f, 0.f, 0.f};
  f32x4 acc[4][4];
#pragma unroll
  for (int m = 0; m < 4; ++m)
#pragma unroll
    for (int n = 0; n < 4; ++n) acc[m][n] = zf;

  // prologue: tiles 0,1 staged; allow tile-1's 6 loads outstanding
  S_B(0); S_A(0); S_B(1); S_A(1);
  if (NT >= 2) { asm volatile("s_waitcnt vmcnt(6)" ::: "memory"); }
  else         { asm volatile("s_waitcnt vmcnt(0)" ::: "memory"); }
  __builtin_amdgcn_s_barrier();

  for (int t = 0; t < NT; ++t) {
    const u16* Ab = As[t & 1];
    const u16* Bb = Bs[t & 1];
    short8 afr[2][2], bfr[4][2];
    // ---- P1: read A m0,m1 + B n0,n1; MFMA q(0,0) ----
#pragma unroll
    for (int m = 0; m < 2; ++m) {
      afr[m][0] = *(const short8*)&Ab[arb + m * 1024 + sk0];
      afr[m][1] = *(const short8*)&Ab[arb + m * 1024 + sk1];
    }
#pragma unroll
    for (int n = 0; n < 2; ++n) {
      bfr[n][0] = *(const short8*)&Bb[brb + n * 1024 + sk0];
      bfr[n][1] = *(const short8*)&Bb[brb + n * 1024 + sk1];
    }
    __builtin_amdgcn_s_barrier();
    asm volatile("s_waitcnt lgkmcnt(0)" ::: "memory");
    __builtin_amdgcn_s_setprio(1);
#pragma unroll
    for (int kk = 0; kk < 2; ++kk)
#pragma unroll
      for (int m = 0; m < 2; ++m)
#pragma unroll
        for (int n = 0; n < 2; ++n)
          acc[m][n] = __builtin_amdgcn_mfma_f32_16x16x32_bf16(afr[m][kk], bfr[n][kk], acc[m][n], 0, 0, 0);
    __builtin_amdgcn_s_setprio(0);
    __builtin_amdgcn_s_barrier();
    // ---- P2: read B n2,n3; MFMA q(0,1) ----
#pragma unroll
    for (int n = 2; n < 4; ++n) {
      bfr[n][0] = *(const short8*)&Bb[brb + n * 1024 + sk0];
      bfr[n][1] = *(const short8*)&Bb[brb + n * 1024 + sk1];
    }
    __builtin_amdgcn_s_barrier();
    asm volatile("s_waitcnt lgkmcnt(0)" ::: "memory");
    __builtin_amdgcn_s_setprio(1);
#pragma unroll
    for (int kk = 0; kk < 2; ++kk)
#pragma unroll
      for (int m = 0; m < 2; ++m)
#pragma unroll
        for (int n = 2; n < 4; ++n)
          acc[m][n] = __builtin_amdgcn_mfma_f32_16x16x32_bf16(afr[m][kk], bfr[n][kk], acc[m][n], 0, 0, 0);
    __builtin_amdgcn_s_setprio(0);
    __builtin_amdgcn_s_barrier();
    // ---- P3: read A m2,m3 (overwrite afr); stage B(t+2); MFMA q(1,0) ----
#pragma unroll
    for (int m = 0; m < 2; ++m) {
      afr[m][0] = *(const short8*)&Ab[arb + (m + 2) * 1024 + sk0];
      afr[m][1] = *(const short8*)&Ab[arb + (m + 2) * 1024 + sk1];
    }
    S_B(t + 2);
    __builtin_amdgcn_s_barrier();
    asm volatile("s_waitcnt lgkmcnt(0)" ::: "memory");
    __builtin_amdgcn_s_setprio(1);
#pragma unroll
    for (int kk = 0; kk < 2; ++kk)
#pragma unroll
      for (int m = 0; m < 2; ++m)
#pragma unroll
        for (int n = 0; n < 2; ++n)
          acc[m + 2][n] = __builtin_amdgcn_mfma_f32_16x16x32_bf16(afr[m][kk], bfr[n][kk], acc[m + 2][n], 0, 0, 0);
    __builtin_amdgcn_s_setprio(0);
    __builtin_amdgcn_s_barrier();
    // ---- P4: stage A(t+2); counted vmcnt; MFMA q(1,1) ----
    S_A(t + 2);
    if (t < NT - 2) { asm volatile("s_waitcnt vmcnt(6)" ::: "memory"); }
    else            { asm volatile("s_waitcnt vmcnt(0)" ::: "memory"); }
    __builtin_amdgcn_s_barrier();
    __builtin_amdgcn_s_setprio(1);
#pragma unroll
    for (int kk = 0; kk < 2; ++kk)
#pragma unroll
      for (int m = 0; m < 2; ++m)
#pragma unroll
        for (int n = 2; n < 4; ++n)
          acc[m + 2][n] = __builtin_amdgcn_mfma_f32_16x16x32_bf16(afr[m][kk], bfr[n][kk], acc[m + 2][n], 0, 0, 0);
    __builtin_amdgcn_s_setprio(0);
    __builtin_amdgcn_s_barrier();
  }
#undef S_A
#undef S_B

  // epilogue (64 elems/thread)
#pragma unroll
  for (int m = 0; m < 4; ++m) {
    int rloc = wm * 64 + m * 16 + g * 4;
#pragma unroll
    for (int n = 0; n < 4; ++n) {
      int gc = n0 + wn * 64 + n * 16 + lr;
      float bcol = biasp[gc];
#pragma unroll
      for (int r = 0; r < 4; ++r) {
        int ridx = m0 + rloc + r;
        float vv = acc[m][n][r] + bcol;
        if constexpr (EPI == 0) {
          outB[(size_t)ridx * ldc + gc] = f2bf(vv);
        } else if constexpr (EPI == 1) {
          size_t off = (size_t)ridx * ldc + gc;
          outF[off] = vv + resid[off];
        } else if constexpr (EPI == 2) {
          if (ridx < M)
            outB[(size_t)(slotBase + ridx) * ldc + gc] = f2bf(gelu_f(vv));
        } else if constexpr (EPI == 3) {
          if (ridx < M)
            outB[(size_t)(slotBase + ridx) * ldc + gc] = f2bf(vv);
        } else {
          if (ridx < M) {
            int tok = list_tok[e * NTOK + ridx];
            float p = list_prob[e * NTOK + ridx];
            atomicAdd(&outF[(size_t)tok * ldc + gc], vv * p);
          }
        }
      }
    }
  }
}

// ---------------- combine: out[t] += p0*part[g0] + p1*part[g1] ----------------
__global__ void combine_kernel(const u16* __restrict__ part, const int* __restrict__ cnt,
                               const int* __restrict__ tok2slot, const float* __restrict__ lprb,
                               float* __restrict__ out) {
  const int t = blockIdx.x, tid = threadIdx.x;
  __shared__ int base[NEXP];
  if (tid == 0) {
    int b = 0;
#pragma unroll
    for (int j = 0; j < NEXP; ++j) { base[j] = b; b += cnt[j]; }
  }
  __syncthreads();
  int c0 = tok2slot[2 * t], c1 = tok2slot[2 * t + 1];
  float p0 = lprb[c0], p1 = lprb[c1];
  int g0 = base[c0 >> 13] + (c0 & 8191);
  int g1 = base[c1 >> 13] + (c1 & 8191);
  us4 a = ((const us4*)(part + (size_t)g0 * 1024))[tid];
  us4 b = ((const us4*)(part + (size_t)g1 * 1024))[tid];
  float4 o = ((const float4*)(out + (size_t)t * 1024))[tid];
  o.x += p0 * bf2f(a[0]) + p1 * bf2f(b[0]);
  o.y += p0 * bf2f(a[1]) + p1 * bf2f(b[1]);
  o.z += p0 * bf2f(a[2]) + p1 * bf2f(b[2]);
  o.w += p0 * bf2f(a[3]) + p1 * bf2f(b[3]);
  ((float4*)(out + (size_t)t * 1024))[tid] = o;
}

// ---------------- host launch ----------------
extern "C" void kernel_launch(void* const* d_in, const int* in_sizes, int n_in,
                              void* d_out, int out_size, void* d_ws, size_t ws_size,
                              hipStream_t stream) {
  const float* x    = (const float*)d_in[0];
  const float* ln1w = (const float*)d_in[1];
  const float* ln1b = (const float*)d_in[2];
  const float* ln2w = (const float*)d_in[3];
  const float* ln2b = (const float*)d_in[4];
  const float* inw  = (const float*)d_in[5];
  const float* inb  = (const float*)d_in[6];
  const float* outw = (const float*)d_in[7];
  const float* outb = (const float*)d_in[8];
  const float* gw   = (const float*)d_in[9];
  const float* gb   = (const float*)d_in[10];
  const float* w1   = (const float*)d_in[11];
  const float* b1   = (const float*)d_in[12];
  const float* w2   = (const float*)d_in[13];
  const float* b2   = (const float*)d_in[14];
  float* out = (float*)d_out;
  char* ws = (char*)d_ws;

  // layout (bytes)
  u16* xn1 = (u16*)(ws + 0);              // 16M
  u16* qkv = (u16*)(ws + 16777216);       // 48M
  u16* ctx = (u16*)(ws + 67108864);       // 16M
  u16* hid = (u16*)(ws + 0);              // 128M (overlaps xn1/qkv/ctx, dead by then)
  u16* xn2 = (u16*)(ws + 134217728);      // 16M
  u16* w1t = (u16*)(ws + 150994944);      // 64M (dead after moe1)
  u16* winb  = (u16*)(ws + 218103808);    // 6M  (dead after qkv gemm)
  u16* woutb = (u16*)(ws + 224395264);    // 2M  (dead after outproj)
  u16* w2t = (u16*)(ws + 134217728);      // 64M, written AFTER moe1, ends 201326592
  u16* part = (u16*)(ws + 201326592);     // 32M (big-ws path only), ends 234881024

  const bool bigWS = ws_size >= 235475456ull;
  int *cnt, *meta, *ltok, *t2s; float* lprb;
  if (bigWS) {
    cnt  = (int*)(ws + 234881024);
    meta = (int*)(ws + 234883072);
    ltok = (int*)(ws + 234887168);
    lprb = (float*)(ws + 235149312);
    t2s  = (int*)(ws + 235411456);
  } else {
    cnt  = (int*)(ws + 226492416);
    meta = (int*)(ws + 226494464);
    ltok = (int*)(ws + 226498560);
    lprb = (float*)(ws + 226760704);
    t2s  = nullptr;
  }

  // weight prep
  cast_kernel<<<3072, 256, 0, stream>>>(inw, winb, 786432);
  cast_kernel<<<1024, 256, 0, stream>>>(outw, woutb, 262144);
  transpose_cast<<<dim3(64, 16, 8), 256, 0, stream>>>(w1, w1t, 1024, 4096);

  // attention sub-block
  ln1_kernel<<<8192, 256, 0, stream>>>(x, ln1w, ln1b, xn1);
  gemmT<0, true><<<dim3(12, 64), 512, 0, stream>>>(xn1, winb, 1024, 1024, 3072, 3072,
      inb, nullptr, nullptr, qkv, nullptr, nullptr, nullptr, nullptr);
  attn_kernel<<<dim3(16, 128), 256, 0, stream>>>(qkv, ctx);
  gemmT<1, true><<<dim3(4, 64), 512, 0, stream>>>(ctx, woutb, 1024, 1024, 1024, 1024,
      outb, x, out, nullptr, nullptr, nullptr, nullptr, nullptr);

  // MoE sub-block (top-2 only)
  hipMemsetAsync(cnt, 0, 32, stream);
  ln2_gate_kernel<<<8192, 256, 0, stream>>>(out, ln2w, ln2b, gw, gb, xn2, cnt, ltok, lprb, t2s);
  plan_kernel<<<1, 64, 0, stream>>>(cnt, meta);
  gemmT<2, true><<<dim3(16, 136), 512, 0, stream>>>(xn2, w1t, 1024, 1024, 4096, 4096,
      b1, nullptr, nullptr, hid, cnt, meta, ltok, lprb);
  transpose_cast<<<dim3(16, 64, 8), 256, 0, stream>>>(w2, w2t, 4096, 1024);
  if (bigWS) {
    gemmT<3, false><<<dim3(4, 136), 512, 0, stream>>>(hid, w2t, 4096, 4096, 1024, 1024,
        b2, nullptr, nullptr, part, cnt, meta, ltok, lprb);
    combine_kernel<<<8192, 256, 0, stream>>>(part, cnt, t2s, lprb, out);
  } else {
    gemmT<4, false><<<dim3(4, 136), 512, 0, stream>>>(hid, w2t, 4096, 4096, 1024, 1024,
        b2, nullptr, out, nullptr, cnt, meta, ltok, lprb);
  }
}

// Round 7
// 1082.256 us; speedup vs baseline: 1.0967x; 1.0967x over previous
//
#include <hip/hip_runtime.h>
#include <math.h>

typedef unsigned short u16;
typedef short short8 __attribute__((ext_vector_type(8)));
typedef float f32x4 __attribute__((ext_vector_type(4)));
typedef unsigned short us4 __attribute__((ext_vector_type(4)));

#define NTOK 8192
#define NEXP 8

__device__ __forceinline__ u16 f2bf(float f) {
  union { float f; unsigned u; } v; v.f = f;
  unsigned r = v.u + 0x7FFFu + ((v.u >> 16) & 1u);
  return (u16)(r >> 16);
}
__device__ __forceinline__ float bf2f(u16 u) {
  union { unsigned u; float f; } v; v.u = ((unsigned)u) << 16; return v.f;
}
__device__ __forceinline__ void gload16(const u16* src, u16* ldsDst) {
  __builtin_amdgcn_global_load_lds(
    (const __attribute__((address_space(1))) unsigned int*)(const void*)src,
    (__attribute__((address_space(3))) unsigned int*)(void*)ldsDst, 16, 0, 0);
}
// fast gelu: A&S 7.1.26 erf (|err|<=1.5e-7)
__device__ __forceinline__ float gelu_f(float v) {
  float ax = fabsf(v) * 0.70710678f;
  float t = __builtin_amdgcn_rcpf(1.0f + 0.3275911f * ax);
  float p = t * (0.254829592f + t * (-0.284496736f + t * (1.421413741f +
            t * (-1.453152027f + t * 1.061405429f))));
  float er = 1.0f - p * __expf(-ax * ax);
  er = copysignf(er, v);
  return 0.5f * v * (1.0f + er);
}

// ---------------- elementwise fp32 -> bf16 cast ----------------
__global__ void cast_kernel(const float* __restrict__ in, u16* __restrict__ out, int n4) {
  int i = blockIdx.x * blockDim.x + threadIdx.x;
  if (i < n4) {
    float4 v = ((const float4*)in)[i];
    us4 o;
    o[0] = f2bf(v.x); o[1] = f2bf(v.y); o[2] = f2bf(v.z); o[3] = f2bf(v.w);
    ((us4*)out)[i] = o;
  }
}

// ------- 64x64 tiled transpose+cast: fp32 in[R][C] -> bf16 out[C][R], blockIdx.z = expert -------
__global__ void transpose_cast(const float* __restrict__ in, u16* __restrict__ out, int R, int C) {
  __shared__ float tile[64][65];
  const size_t eoff = (size_t)blockIdx.z * (size_t)R * (size_t)C;
  in += eoff; out += eoff;
  const int rb = blockIdx.y * 64, cb = blockIdx.x * 64;
  const int tid = threadIdx.x;
  const int lr4 = tid >> 4;
  const int lc4 = (tid & 15) * 4;
#pragma unroll
  for (int p = 0; p < 4; ++p) {
    float4 v = *(const float4*)&in[(size_t)(rb + p * 16 + lr4) * C + cb + lc4];
    tile[p * 16 + lr4][lc4 + 0] = v.x;
    tile[p * 16 + lr4][lc4 + 1] = v.y;
    tile[p * 16 + lr4][lc4 + 2] = v.z;
    tile[p * 16 + lr4][lc4 + 3] = v.w;
  }
  __syncthreads();
  const int oc = tid >> 3;
  const int orr = (tid & 7) * 8;
#pragma unroll
  for (int p = 0; p < 2; ++p) {
    int c = p * 32 + oc;
    short8 o;
#pragma unroll
    for (int j = 0; j < 8; ++j) o[j] = (short)f2bf(tile[orr + j][c]);
    *(short8*)&out[(size_t)(cb + c) * R + rb + orr] = o;
  }
}

// ---------------- LayerNorm1: fp32 row -> bf16 row ----------------
__global__ void ln1_kernel(const float* __restrict__ x, const float* __restrict__ w,
                           const float* __restrict__ b, u16* __restrict__ xn) {
  const int t = blockIdx.x, tid = threadIdx.x;
  __shared__ float red[8];
  float4 v = ((const float4*)(x + (size_t)t * 1024))[tid];
  float s  = v.x + v.y + v.z + v.w;
  float sq = v.x*v.x + v.y*v.y + v.z*v.z + v.w*v.w;
#pragma unroll
  for (int m = 1; m < 64; m <<= 1) { s += __shfl_xor(s, m, 64); sq += __shfl_xor(sq, m, 64); }
  if ((tid & 63) == 0) { red[tid >> 6] = s; red[4 + (tid >> 6)] = sq; }
  __syncthreads();
  float S = red[0] + red[1] + red[2] + red[3];
  float Q = red[4] + red[5] + red[6] + red[7];
  float mu  = S * (1.0f / 1024.0f);
  float var = Q * (1.0f / 1024.0f) - mu * mu;
  float inv = rsqrtf(var + 1e-5f);
  float4 wv = ((const float4*)w)[tid];
  float4 bv = ((const float4*)b)[tid];
  us4 o;
  o[0] = f2bf((v.x - mu) * inv * wv.x + bv.x);
  o[1] = f2bf((v.y - mu) * inv * wv.y + bv.y);
  o[2] = f2bf((v.z - mu) * inv * wv.z + bv.z);
  o[3] = f2bf((v.w - mu) * inv * wv.w + bv.w);
  ((us4*)(xn + (size_t)t * 1024))[tid] = o;
}

// -------- LayerNorm2 + gate + top-2 routing (fp32 gate for routing fidelity) --------
__global__ void ln2_gate_kernel(const float* __restrict__ x2, const float* __restrict__ w,
                                const float* __restrict__ b, const float* __restrict__ gw,
                                const float* __restrict__ gb, u16* __restrict__ xn2,
                                int* __restrict__ cnt, int* __restrict__ list_tok,
                                float* __restrict__ list_prob, int* __restrict__ tok2slot) {
  const int t = blockIdx.x, tid = threadIdx.x;
  __shared__ float red[8];
  __shared__ float logits[NEXP];
  __shared__ float xrow[1024];
  float4 v = ((const float4*)(x2 + (size_t)t * 1024))[tid];
  float s  = v.x + v.y + v.z + v.w;
  float sq = v.x*v.x + v.y*v.y + v.z*v.z + v.w*v.w;
#pragma unroll
  for (int m = 1; m < 64; m <<= 1) { s += __shfl_xor(s, m, 64); sq += __shfl_xor(sq, m, 64); }
  if ((tid & 63) == 0) { red[tid >> 6] = s; red[4 + (tid >> 6)] = sq; }
  __syncthreads();
  float S = red[0] + red[1] + red[2] + red[3];
  float Q = red[4] + red[5] + red[6] + red[7];
  float mu  = S * (1.0f / 1024.0f);
  float var = Q * (1.0f / 1024.0f) - mu * mu;
  float inv = rsqrtf(var + 1e-5f);
  float4 wv = ((const float4*)w)[tid];
  float4 bv = ((const float4*)b)[tid];
  float n0 = (v.x - mu) * inv * wv.x + bv.x;
  float n1 = (v.y - mu) * inv * wv.y + bv.y;
  float n2 = (v.z - mu) * inv * wv.z + bv.z;
  float n3 = (v.w - mu) * inv * wv.w + bv.w;
  xrow[tid*4+0] = n0; xrow[tid*4+1] = n1; xrow[tid*4+2] = n2; xrow[tid*4+3] = n3;
  us4 o; o[0] = f2bf(n0); o[1] = f2bf(n1); o[2] = f2bf(n2); o[3] = f2bf(n3);
  ((us4*)(xn2 + (size_t)t * 1024))[tid] = o;
  __syncthreads();
  int e = tid >> 5, l32 = tid & 31;
  const float* gwe = gw + e * 1024;
  float part = 0.0f;
  for (int i = l32; i < 1024; i += 32) part += xrow[i] * gwe[i];
#pragma unroll
  for (int m = 1; m < 32; m <<= 1) part += __shfl_xor(part, m, 64);
  if (l32 == 0) logits[e] = part + gb[e];
  __syncthreads();
  if (tid == 0) {
    float v0 = -1e30f; int e0 = 0;
#pragma unroll
    for (int i = 0; i < NEXP; ++i) { float L = logits[i]; if (L > v0) { v0 = L; e0 = i; } }
    float v1 = -1e30f; int e1 = 0;
#pragma unroll
    for (int i = 0; i < NEXP; ++i) { if (i == e0) continue; float L = logits[i]; if (L > v1) { v1 = L; e1 = i; } }
    float texp = expf(v1 - v0);
    float p0 = 1.0f / (1.0f + texp);
    float p1 = texp / (1.0f + texp);
    int s0 = atomicAdd(&cnt[e0], 1);
    list_tok[e0 * NTOK + s0] = t; list_prob[e0 * NTOK + s0] = p0;
    int s1 = atomicAdd(&cnt[e1], 1);
    list_tok[e1 * NTOK + s1] = t; list_prob[e1 * NTOK + s1] = p1;
    if (tok2slot) {
      tok2slot[2 * t]     = e0 * NTOK + s0;
      tok2slot[2 * t + 1] = e1 * NTOK + s1;
    }
  }
}

// ----- plan kernel: meta[0..7]=slotBase, meta[8]=planCount, meta[16+2i]=e, meta[17+2i]=m0 -----
__global__ void plan_kernel(const int* __restrict__ cnt, int* __restrict__ meta) {
  if (threadIdx.x == 0) {
    int base = 0, p = 0;
    for (int e = 0; e < NEXP; ++e) {
      meta[e] = base;
      int c = cnt[e];
      base += c;
      int nm = (c + 127) >> 7;
      for (int i = 0; i < nm; ++i) { meta[16 + 2 * p] = e; meta[17 + 2 * p] = i << 7; ++p; }
    }
    meta[8] = p;
  }
}

// ---------------- flash attention: one (b,h), 64 q-rows per block ----------------
__launch_bounds__(256)
__global__ void attn_kernel(const u16* __restrict__ qkv, u16* __restrict__ ctx) {
  const int bh = blockIdx.y;
  const int b = bh >> 4, h = bh & 15;
  const int q0 = blockIdx.x * 64;
  const int tokBase = b * 1024;
  __shared__ __align__(16) u16 Qs[64 * 72];
  __shared__ __align__(16) u16 Ks[64 * 72];
  __shared__ __align__(16) u16 Vts[64 * 72];
  __shared__ __align__(16) u16 Ps[64 * 72];
  const int tid = threadIdx.x;
  const int wave = tid >> 6, lane = tid & 63, g = lane >> 4, lr = lane & 15;

  {
    int r = tid >> 2, d0 = (tid & 3) * 16;
    const u16* src = qkv + (size_t)(tokBase + q0 + r) * 3072 + h * 64 + d0;
    *(short8*)&Qs[r * 72 + d0]     = *(const short8*)src;
    *(short8*)&Qs[r * 72 + d0 + 8] = *(const short8*)(src + 8);
  }
  __syncthreads();
  short8 aq0 = *(const short8*)&Qs[(wave * 16 + lr) * 72 + g * 8];
  short8 aq1 = *(const short8*)&Qs[(wave * 16 + lr) * 72 + 32 + g * 8];

  const f32x4 zf = {0.f, 0.f, 0.f, 0.f};
  f32x4 Ofr[4] = {zf, zf, zf, zf};
  float m_run[4], l_run[4];
#pragma unroll
  for (int r = 0; r < 4; ++r) { m_run[r] = -1e30f; l_run[r] = 0.f; }

  for (int kt = 0; kt < 1024; kt += 64) {
    __syncthreads();
    {
      int r = tid >> 2, d0 = (tid & 3) * 16;
      const u16* ksrc = qkv + (size_t)(tokBase + kt + r) * 3072 + 1024 + h * 64 + d0;
      *(short8*)&Ks[r * 72 + d0]     = *(const short8*)ksrc;
      *(short8*)&Ks[r * 72 + d0 + 8] = *(const short8*)(ksrc + 8);
      const u16* vsrc = qkv + (size_t)(tokBase + kt + r) * 3072 + 2048 + h * 64 + d0;
      short8 v0 = *(const short8*)vsrc, v1 = *(const short8*)(vsrc + 8);
#pragma unroll
      for (int j = 0; j < 8; ++j) Vts[(d0 + j) * 72 + r] = (u16)v0[j];
#pragma unroll
      for (int j = 0; j < 8; ++j) Vts[(d0 + 8 + j) * 72 + r] = (u16)v1[j];
    }
    __syncthreads();
    f32x4 sf[4];
#pragma unroll
    for (int n = 0; n < 4; ++n) sf[n] = zf;
#pragma unroll
    for (int n = 0; n < 4; ++n) {
      short8 bk0 = *(const short8*)&Ks[(n * 16 + lr) * 72 + g * 8];
      short8 bk1 = *(const short8*)&Ks[(n * 16 + lr) * 72 + 32 + g * 8];
      sf[n] = __builtin_amdgcn_mfma_f32_16x16x32_bf16(aq0, bk0, sf[n], 0, 0, 0);
      sf[n] = __builtin_amdgcn_mfma_f32_16x16x32_bf16(aq1, bk1, sf[n], 0, 0, 0);
    }
#pragma unroll
    for (int n = 0; n < 4; ++n)
#pragma unroll
      for (int r = 0; r < 4; ++r) sf[n][r] *= 0.125f;
    float mnew[4], sc[4];
#pragma unroll
    for (int r = 0; r < 4; ++r) {
      float t0 = fmaxf(fmaxf(sf[0][r], sf[1][r]), fmaxf(sf[2][r], sf[3][r]));
#pragma unroll
      for (int msk = 1; msk < 16; msk <<= 1) t0 = fmaxf(t0, __shfl_xor(t0, msk, 64));
      mnew[r] = fmaxf(m_run[r], t0);
      sc[r] = __expf(m_run[r] - mnew[r]);
      m_run[r] = mnew[r];
    }
#pragma unroll
    for (int n = 0; n < 4; ++n)
#pragma unroll
      for (int r = 0; r < 4; ++r) sf[n][r] = __expf(sf[n][r] - mnew[r]);
#pragma unroll
    for (int r = 0; r < 4; ++r) {
      float s0 = sf[0][r] + sf[1][r] + sf[2][r] + sf[3][r];
#pragma unroll
      for (int msk = 1; msk < 16; msk <<= 1) s0 += __shfl_xor(s0, msk, 64);
      l_run[r] = l_run[r] * sc[r] + s0;
    }
#pragma unroll
    for (int nd = 0; nd < 4; ++nd)
#pragma unroll
      for (int r = 0; r < 4; ++r) Ofr[nd][r] *= sc[r];
#pragma unroll
    for (int n = 0; n < 4; ++n)
#pragma unroll
      for (int r = 0; r < 4; ++r)
        Ps[(wave * 16 + g * 4 + r) * 72 + n * 16 + lr] = f2bf(sf[n][r]);
    __syncthreads();
    short8 ap0 = *(const short8*)&Ps[(wave * 16 + lr) * 72 + g * 8];
    short8 ap1 = *(const short8*)&Ps[(wave * 16 + lr) * 72 + 32 + g * 8];
#pragma unroll
    for (int nd = 0; nd < 4; ++nd) {
      short8 bv0 = *(const short8*)&Vts[(nd * 16 + lr) * 72 + g * 8];
      short8 bv1 = *(const short8*)&Vts[(nd * 16 + lr) * 72 + 32 + g * 8];
      Ofr[nd] = __builtin_amdgcn_mfma_f32_16x16x32_bf16(ap0, bv0, Ofr[nd], 0, 0, 0);
      Ofr[nd] = __builtin_amdgcn_mfma_f32_16x16x32_bf16(ap1, bv1, Ofr[nd], 0, 0, 0);
    }
  }
#pragma unroll
  for (int nd = 0; nd < 4; ++nd)
#pragma unroll
    for (int r = 0; r < 4; ++r) {
      int tok = tokBase + q0 + wave * 16 + g * 4 + r;
      int col = h * 64 + nd * 16 + lr;
      ctx[(size_t)tok * 1024 + col] = f2bf(Ofr[nd][r] / l_run[r]);
    }
}

// ======= PERSISTENT 128x128xBK64 bf16 GEMM, C = A @ B^T, 4 waves (2x2), counted vmcnt =======
// Each block owns n-column bx and a CONTIGUOUS chunk of m-slots; one flat pipelined loop over
// all (slot, k-tile) pairs: stage(it+2) into buf[it&1] (read-completion barrier first),
// vmcnt(8) counted wait (drain only in last 3 iters), epilogue at slot boundary overlaps
// the already-in-flight next-slot loads. Rolling slot state prefetched one slot ahead.
// EPI 0: qkv (bias, bf16)  1: outproj (bias+resid, fp32)  2: moe1 (gather, gelu)
// EPI 3: moe2 -> part bf16   4: moe2 atomic fallback
template<int EPI>
__launch_bounds__(256, 2)
__global__ void gemmP(const u16* __restrict__ Abase, const u16* __restrict__ Bbase,
                      int K, int lda, int N, int ldc, int nSlotsFixed,
                      const float* __restrict__ bias,
                      const float* __restrict__ resid,
                      float* __restrict__ outF,
                      u16* __restrict__ outB,
                      const int* __restrict__ cnt,
                      const int* __restrict__ meta,
                      const int* __restrict__ list_tok,
                      const float* __restrict__ list_prob) {
  const int gx = gridDim.x, G = gridDim.y;
  const int nwg = gx * G;
  // bijective XCD chunk remap over bx-major linear id (same-bx blocks contiguous per XCD)
  int orig = blockIdx.y + blockIdx.x * G;
  int q8 = nwg >> 3, r8 = nwg & 7, xcd = orig & 7, lid = orig >> 3;
  int wg = (xcd < r8 ? xcd * (q8 + 1) : r8 * (q8 + 1) + (xcd - r8) * q8) + lid;
  const int bx = wg / G, gidx = wg % G;
  const int n0 = bx * 128;

  const int S = (EPI >= 2) ? meta[8] : nSlotsFixed;
  const int cpb = (S + G - 1) / G;
  const int sBeg = gidx * cpb;
  int sEnd = sBeg + cpb; if (sEnd > S) sEnd = S;
  if (sBeg >= sEnd) return;
  const int nslots = sEnd - sBeg;
  const int NT = K >> 6;
  const int ntLog = 31 - __builtin_clz((unsigned)NT);
  const int nIt = nslots << ntLog;

  __shared__ __align__(16) u16 As[2][8192];   // 2 x 128x64
  __shared__ __align__(16) u16 Bs[2][8192];

  const int tid = threadIdx.x;
  const int wave = tid >> 6, lane = tid & 63, gp = lane >> 4, lr = lane & 15;
  const int wm = wave >> 1, wn = wave & 1;

  // B staging offsets (row within panel) -- slot-independent
  unsigned boff[4];
#pragma unroll
  for (int i = 0; i < 4; ++i) {
    int ci = i * 256 + tid;
    int row = ci >> 3, c = ci & 7;
    int lc = c ^ (row & 7);
    boff[i] = (unsigned)(n0 + row) * (unsigned)K + (unsigned)(lc << 3);
  }

  // rolling slot state: C = current, N = next
  int eC, m0C, MC, sbC; const u16* BwC; unsigned aoffC[4];
  int eN, m0N, MN, sbN; const u16* BwN; unsigned aoffN[4];

  auto loadSlot = [&](int s, int& e, int& m0, int& M, int& sb, const u16*& Bw, unsigned (&ao)[4]) {
    if constexpr (EPI >= 2) {
      e = meta[16 + 2 * s]; m0 = meta[17 + 2 * s]; M = cnt[e]; sb = meta[e];
      Bw = Bbase + (size_t)e * (size_t)N * (size_t)K;
    } else {
      e = 0; m0 = s * 128; M = NTOK; sb = 0; Bw = Bbase;
    }
#pragma unroll
    for (int i = 0; i < 4; ++i) {
      int ci = i * 256 + tid;
      int row = ci >> 3, c = ci & 7;
      int lc = c ^ (row & 7);
      int arow;
      if constexpr (EPI == 2) {
        int r = m0 + row; if (r > M - 1) r = M - 1;
        arow = list_tok[e * NTOK + r];
      } else if constexpr (EPI >= 3) {
        int r = m0 + row; if (r > M - 1) r = M - 1;
        arow = sb + r;
      } else {
        arow = m0 + row;
      }
      ao[i] = (unsigned)arow * (unsigned)lda + (unsigned)(lc << 3);
    }
  };

  loadSlot(sBeg, eC, m0C, MC, sbC, BwC, aoffC);
  if (nslots > 1) loadSlot(sBeg + 1, eN, m0N, MN, sbN, BwN, aoffN);
  else { eN = eC; m0N = m0C; MN = MC; sbN = sbC; BwN = BwC;
#pragma unroll
         for (int i = 0; i < 4; ++i) aoffN[i] = aoffC[i]; }

  const int sw = lr & 7;
  const int arb = (wm * 64 + lr) * 64;
  const int brb = (wn * 64 + lr) * 64;
  const int sk0 = (gp ^ sw) * 8;
  const int sk1 = ((4 + gp) ^ sw) * 8;

  const f32x4 zf = {0.f, 0.f, 0.f, 0.f};
  f32x4 acc[4][4];
#pragma unroll
  for (int m = 0; m < 4; ++m)
#pragma unroll
    for (int n = 0; n < 4; ++n) acc[m][n] = zf;

  // prologue: stage tiles 0 and 1 (both slot sBeg; NT >= 16 > 1)
#pragma unroll
  for (int tt = 0; tt < 2; ++tt) {
    int kt = tt << 6;
#pragma unroll
    for (int i = 0; i < 4; ++i) {
      gload16(Abase + aoffC[i] + kt, &As[tt][(i * 256 + wave * 64) << 3]);
      gload16(BwC + boff[i] + kt, &Bs[tt][(i * 256 + wave * 64) << 3]);
    }
  }
  asm volatile("s_waitcnt vmcnt(8)" ::: "memory");
  __builtin_amdgcn_s_barrier();

  for (int it = 0; it < nIt; ++it) {
    const int sRel = it >> ntLog;
    const int t = it & (NT - 1);
    const u16* Ab = As[it & 1];
    const u16* Bb = Bs[it & 1];
    short8 af[4][2], bf[4][2];
#pragma unroll
    for (int m = 0; m < 4; ++m) {
      af[m][0] = *(const short8*)&Ab[arb + m * 1024 + sk0];
      af[m][1] = *(const short8*)&Ab[arb + m * 1024 + sk1];
    }
#pragma unroll
    for (int n = 0; n < 4; ++n) {
      bf[n][0] = *(const short8*)&Bb[brb + n * 1024 + sk0];
      bf[n][1] = *(const short8*)&Bb[brb + n * 1024 + sk1];
    }
    asm volatile("s_waitcnt lgkmcnt(0)" ::: "memory");
    __builtin_amdgcn_s_barrier();   // all waves done reading buf[it&1] -> safe to overwrite
    // stage tile it+2 into buf[it&1]
    {
      int it2 = it + 2;
      if (it2 < nIt) {
        bool nx = (it2 >> ntLog) != sRel;
        int kt2 = (it2 & (NT - 1)) << 6;
        int b2 = it2 & 1;
#pragma unroll
        for (int i = 0; i < 4; ++i) {
          unsigned ao = nx ? aoffN[i] : aoffC[i];
          const u16* bw = nx ? BwN : BwC;
          gload16(Abase + ao + kt2, &As[b2][(i * 256 + wave * 64) << 3]);
          gload16(bw + boff[i] + kt2, &Bs[b2][(i * 256 + wave * 64) << 3]);
        }
      }
    }
    __builtin_amdgcn_s_setprio(1);
#pragma unroll
    for (int kk = 0; kk < 2; ++kk)
#pragma unroll
      for (int m = 0; m < 4; ++m)
#pragma unroll
        for (int n = 0; n < 4; ++n)
          acc[m][n] = __builtin_amdgcn_mfma_f32_16x16x32_bf16(af[m][kk], bf[n][kk], acc[m][n], 0, 0, 0);
    __builtin_amdgcn_s_setprio(0);
    if (it < nIt - 3) { asm volatile("s_waitcnt vmcnt(8)" ::: "memory"); }
    else              { asm volatile("s_waitcnt vmcnt(0)" ::: "memory"); }
    __builtin_amdgcn_s_barrier();

    if (t == NT - 1) {
      // ---- epilogue for slot (sBeg + sRel): overlaps in-flight next-slot loads ----
#pragma unroll
      for (int m = 0; m < 4; ++m) {
        int rloc = wm * 64 + m * 16 + gp * 4;
#pragma unroll
        for (int n = 0; n < 4; ++n) {
          int gc = n0 + wn * 64 + n * 16 + lr;
          float bcol;
          if constexpr (EPI >= 2) bcol = bias[(size_t)eC * N + gc];
          else bcol = bias[gc];
#pragma unroll
          for (int r = 0; r < 4; ++r) {
            int ridx = m0C + rloc + r;
            float vv = acc[m][n][r] + bcol;
            if constexpr (EPI == 0) {
              outB[(size_t)ridx * ldc + gc] = f2bf(vv);
            } else if constexpr (EPI == 1) {
              size_t off = (size_t)ridx * ldc + gc;
              outF[off] = vv + resid[off];
            } else if constexpr (EPI == 2) {
              if (ridx < MC)
                outB[(size_t)(sbC + ridx) * ldc + gc] = f2bf(gelu_f(vv));
            } else if constexpr (EPI == 3) {
              if (ridx < MC)
                outB[(size_t)(sbC + ridx) * ldc + gc] = f2bf(vv);
            } else {
              if (ridx < MC) {
                int tok = list_tok[eC * NTOK + ridx];
                float p = list_prob[eC * NTOK + ridx];
                atomicAdd(&outF[(size_t)tok * ldc + gc], vv * p);
              }
            }
            acc[m][n][r] = 0.f;
          }
        }
      }
      // shift slot state, prefetch slot sBeg+sRel+2
      eC = eN; m0C = m0N; MC = MN; sbC = sbN; BwC = BwN;
#pragma unroll
      for (int i = 0; i < 4; ++i) aoffC[i] = aoffN[i];
      int s2 = sBeg + sRel + 2;
      if (s2 < sEnd) loadSlot(s2, eN, m0N, MN, sbN, BwN, aoffN);
    }
  }
}

// ---------------- combine: out[t] += p0*part[g0] + p1*part[g1] ----------------
__global__ void combine_kernel(const u16* __restrict__ part, const int* __restrict__ cnt,
                               const int* __restrict__ tok2slot, const float* __restrict__ lprb,
                               float* __restrict__ out) {
  const int t = blockIdx.x, tid = threadIdx.x;
  __shared__ int base[NEXP];
  if (tid == 0) {
    int b = 0;
#pragma unroll
    for (int j = 0; j < NEXP; ++j) { base[j] = b; b += cnt[j]; }
  }
  __syncthreads();
  int c0 = tok2slot[2 * t], c1 = tok2slot[2 * t + 1];
  float p0 = lprb[c0], p1 = lprb[c1];
  int g0 = base[c0 >> 13] + (c0 & 8191);
  int g1 = base[c1 >> 13] + (c1 & 8191);
  us4 a = ((const us4*)(part + (size_t)g0 * 1024))[tid];
  us4 b = ((const us4*)(part + (size_t)g1 * 1024))[tid];
  float4 o = ((const float4*)(out + (size_t)t * 1024))[tid];
  o.x += p0 * bf2f(a[0]) + p1 * bf2f(b[0]);
  o.y += p0 * bf2f(a[1]) + p1 * bf2f(b[1]);
  o.z += p0 * bf2f(a[2]) + p1 * bf2f(b[2]);
  o.w += p0 * bf2f(a[3]) + p1 * bf2f(b[3]);
  ((float4*)(out + (size_t)t * 1024))[tid] = o;
}

// ---------------- host launch ----------------
extern "C" void kernel_launch(void* const* d_in, const int* in_sizes, int n_in,
                              void* d_out, int out_size, void* d_ws, size_t ws_size,
                              hipStream_t stream) {
  const float* x    = (const float*)d_in[0];
  const float* ln1w = (const float*)d_in[1];
  const float* ln1b = (const float*)d_in[2];
  const float* ln2w = (const float*)d_in[3];
  const float* ln2b = (const float*)d_in[4];
  const float* inw  = (const float*)d_in[5];
  const float* inb  = (const float*)d_in[6];
  const float* outw = (const float*)d_in[7];
  const float* outb = (const float*)d_in[8];
  const float* gw   = (const float*)d_in[9];
  const float* gb   = (const float*)d_in[10];
  const float* w1   = (const float*)d_in[11];
  const float* b1   = (const float*)d_in[12];
  const float* w2   = (const float*)d_in[13];
  const float* b2   = (const float*)d_in[14];
  float* out = (float*)d_out;
  char* ws = (char*)d_ws;

  // layout (bytes)
  u16* xn1 = (u16*)(ws + 0);              // 16M
  u16* qkv = (u16*)(ws + 16777216);       // 48M
  u16* ctx = (u16*)(ws + 67108864);       // 16M
  u16* hid = (u16*)(ws + 0);              // 128M (overlaps xn1/qkv/ctx, dead by then)
  u16* xn2 = (u16*)(ws + 134217728);      // 16M
  u16* w1t = (u16*)(ws + 150994944);      // 64M (dead after moe1)
  u16* winb  = (u16*)(ws + 218103808);    // 6M  (dead after qkv gemm)
  u16* woutb = (u16*)(ws + 224395264);    // 2M  (dead after outproj)
  u16* w2t = (u16*)(ws + 134217728);      // 64M, written AFTER moe1, ends 201326592
  u16* part = (u16*)(ws + 201326592);     // 32M (big-ws path only), ends 234881024

  const bool bigWS = ws_size >= 235475456ull;
  int *cnt, *meta, *ltok, *t2s; float* lprb;
  if (bigWS) {
    cnt  = (int*)(ws + 234881024);
    meta = (int*)(ws + 234883072);
    ltok = (int*)(ws + 234887168);
    lprb = (float*)(ws + 235149312);
    t2s  = (int*)(ws + 235411456);
  } else {
    cnt  = (int*)(ws + 226492416);
    meta = (int*)(ws + 226494464);
    ltok = (int*)(ws + 226498560);
    lprb = (float*)(ws + 226760704);
    t2s  = nullptr;
  }

  // weight prep
  cast_kernel<<<3072, 256, 0, stream>>>(inw, winb, 786432);
  cast_kernel<<<1024, 256, 0, stream>>>(outw, woutb, 262144);
  transpose_cast<<<dim3(64, 16, 8), 256, 0, stream>>>(w1, w1t, 1024, 4096);

  // attention sub-block
  ln1_kernel<<<8192, 256, 0, stream>>>(x, ln1w, ln1b, xn1);
  gemmP<0><<<dim3(24, 16), 256, 0, stream>>>(xn1, winb, 1024, 1024, 3072, 3072, 64,
      inb, nullptr, nullptr, qkv, nullptr, nullptr, nullptr, nullptr);
  attn_kernel<<<dim3(16, 128), 256, 0, stream>>>(qkv, ctx);
  gemmP<1><<<dim3(8, 32), 256, 0, stream>>>(ctx, woutb, 1024, 1024, 1024, 1024, 64,
      outb, x, out, nullptr, nullptr, nullptr, nullptr, nullptr);

  // MoE sub-block (top-2 only)
  hipMemsetAsync(cnt, 0, 32, stream);
  ln2_gate_kernel<<<8192, 256, 0, stream>>>(out, ln2w, ln2b, gw, gb, xn2, cnt, ltok, lprb, t2s);
  plan_kernel<<<1, 64, 0, stream>>>(cnt, meta);
  gemmP<2><<<dim3(32, 16), 256, 0, stream>>>(xn2, w1t, 1024, 1024, 4096, 4096, 0,
      b1, nullptr, nullptr, hid, cnt, meta, ltok, lprb);
  transpose_cast<<<dim3(16, 64, 8), 256, 0, stream>>>(w2, w2t, 4096, 1024);
  if (bigWS) {
    gemmP<3><<<dim3(8, 64), 256, 0, stream>>>(hid, w2t, 4096, 4096, 1024, 1024, 0,
        b2, nullptr, nullptr, part, cnt, meta, ltok, lprb);
    combine_kernel<<<8192, 256, 0, stream>>>(part, cnt, t2s, lprb, out);
  } else {
    gemmP<4><<<dim3(8, 64), 256, 0, stream>>>(hid, w2t, 4096, 4096, 1024, 1024, 0,
        b2, nullptr, out, nullptr, cnt, meta, ltok, lprb);
  }
}